// Round 2
// baseline (757.840 us; speedup 1.0000x reference)
//
#include <hip/hip_runtime.h>
#include <hip/hip_bf16.h>

typedef __bf16 bf16;
typedef __bf16 bf16x8 __attribute__((ext_vector_type(8)));
typedef float floatx4 __attribute__((ext_vector_type(4)));

#define BATCH 64
#define S576  576
#define D1024 1024
#define MPAD  640   // 5 * 128, covers L <= 575
#define KPAD  576   // 18 * 32

// Build both DCT matrices as zero-padded bf16 [MPAD][KPAD]:
//  A1[m][s] = C576[m,s]        (m < L, else 0)          for x_dct = C @ x
//  A2[l][k] = C_L[k,l]         (l < L && k < L, else 0) for recon = C_L^T @ x_dct_trunc
__global__ void build_dct_kernel(bf16* __restrict__ A1, bf16* __restrict__ A2, int L) {
    int idx = blockIdx.x * blockDim.x + threadIdx.x;
    if (idx >= MPAD * KPAD) return;
    int m = idx / KPAD;
    int s = idx % KPAD;
    const double PI = 3.14159265358979323846;
    float v1 = 0.0f;
    if (m < L) {
        double scale = (m == 0) ? sqrt(1.0 / 576.0) : sqrt(2.0 / 576.0);
        v1 = (float)(cos(PI / 576.0 * ((double)s + 0.5) * (double)m) * scale);
    }
    A1[idx] = (bf16)v1;
    float v2 = 0.0f;
    if (m < L && s < L) {
        double dL = (double)L;
        double scale = (s == 0) ? sqrt(1.0 / dL) : sqrt(2.0 / dL);
        v2 = (float)(cos(PI / dL * ((double)m + 0.5) * (double)s) * scale);
    }
    A2[idx] = (bf16)v2;
}

// Batched GEMM: Out[b][m][n] = sum_k A[m][k] * B[b][k][n], float32 in/out for B/Out,
// bf16 MFMA internally. A: bf16 [MPAD][KPAD] zero-padded.
// B: f32 [BATCH][bRows][1024]. GUARD_K: zero-fill k >= bRows (GEMM2 truncation).
// Tile: 128x128, BK=32, 256 threads = 4 waves in 2x2, each wave 4x4 MFMAs 16x16x32 bf16.
template<bool GUARD_K>
__global__ __launch_bounds__(256)
void dct_gemm(const bf16* __restrict__ A, const float* __restrict__ B,
              float* __restrict__ Out, int L, int Kchunks, int bRows)
{
    // stride 40 elements = 80 B: multiple of 16 B (aligned ds_read_b128),
    // rows spread across banks (max 2-way aliasing for wave64 = free)
    __shared__ __align__(16) bf16 Asm[128][40];
    __shared__ __align__(16) bf16 Bsm[128][40];

    const int tid  = threadIdx.x;
    const int lane = tid & 63;
    const int wave = tid >> 6;
    const int wm   = (wave >> 1) * 64;   // wave row offset in tile
    const int wn   = (wave & 1) * 64;    // wave col offset in tile
    const int quad = lane >> 4;
    const int l16  = lane & 15;

    const int n0 = blockIdx.x * 128;
    const int m0 = blockIdx.y * 128;
    const int batch = blockIdx.z;

    const float* __restrict__ Bf = B + (size_t)batch * (size_t)bRows * D1024;

    floatx4 acc[4][4];
    #pragma unroll
    for (int i = 0; i < 4; ++i)
        #pragma unroll
        for (int j = 0; j < 4; ++j)
            #pragma unroll
            for (int r = 0; r < 4; ++r)
                acc[i][j][r] = 0.0f;

    for (int kc = 0; kc < Kchunks; ++kc) {
        const int k0 = kc * 32;

        // ---- stage A tile [128][32]: 512 16B-chunks, 2 per thread ----
        #pragma unroll
        for (int it = 0; it < 2; ++it) {
            int c = it * 256 + tid;
            int m = c >> 2;          // 0..127
            int q = c & 3;           // 16B chunk within row
            bf16x8 av = *(const bf16x8*)(A + (size_t)(m0 + m) * KPAD + (k0 + q * 8));
            *(bf16x8*)&Asm[m][q * 8] = av;
        }

        // ---- stage B tile transposed -> Bsm[d][k], f32 -> bf16 cast ----
        // thread g: one d, 8 consecutive k. Lanes span consecutive d:
        // each global load instruction covers 256 B contiguous.
        #pragma unroll
        for (int it = 0; it < 2; ++it) {
            int g  = it * 256 + tid;     // 0..511
            int d  = g & 127;
            int s0 = (g >> 7) * 8;       // 0,8 / 16,24
            bf16x8 pk;
            #pragma unroll
            for (int j = 0; j < 8; ++j) {
                int k = k0 + s0 + j;     // wave-uniform guard
                float v = (!GUARD_K || k < bRows)
                              ? Bf[(size_t)k * D1024 + (n0 + d)] : 0.0f;
                pk[j] = (bf16)v;
            }
            *(bf16x8*)&Bsm[d][s0] = pk;
        }
        __syncthreads();

        // ---- fragments: A[m=l16][k=quad*8+j], B[k=quad*8+j][n=l16] ----
        bf16x8 af[4], bfr[4];
        #pragma unroll
        for (int mt = 0; mt < 4; ++mt)
            af[mt] = *(const bf16x8*)&Asm[wm + mt * 16 + l16][quad * 8];
        #pragma unroll
        for (int nt = 0; nt < 4; ++nt)
            bfr[nt] = *(const bf16x8*)&Bsm[wn + nt * 16 + l16][quad * 8];

        #pragma unroll
        for (int mt = 0; mt < 4; ++mt)
            #pragma unroll
            for (int nt = 0; nt < 4; ++nt)
                acc[mt][nt] = __builtin_amdgcn_mfma_f32_16x16x32_bf16(
                                  af[mt], bfr[nt], acc[mt][nt], 0, 0, 0);
        __syncthreads();
    }

    // ---- epilogue: C/D layout col = l16, row = quad*4 + r; fp32 stores ----
    const size_t obase = (size_t)batch * (size_t)L * D1024;
    #pragma unroll
    for (int mt = 0; mt < 4; ++mt) {
        #pragma unroll
        for (int r = 0; r < 4; ++r) {
            int m = m0 + wm + mt * 16 + quad * 4 + r;
            if (m < L) {
                size_t rowoff = obase + (size_t)m * D1024;
                #pragma unroll
                for (int nt = 0; nt < 4; ++nt) {
                    int n = n0 + wn + nt * 16 + l16;
                    Out[rowoff + n] = acc[mt][nt][r];
                }
            }
        }
    }
}

extern "C" void kernel_launch(void* const* d_in, const int* in_sizes, int n_in,
                              void* d_out, int out_size, void* d_ws, size_t ws_size,
                              hipStream_t stream)
{
    const float* x = (const float*)d_in[0];
    float* out = (float*)d_out;   // fp32: reference outputs are fp16/fp32, not bf16

    // out = [recon (64*L*1024)] ++ [x_dct_trunc (64*L*1024)], both fp32
    const int L = out_size / (2 * BATCH * D1024);
    if (L <= 0) return;

    bf16* A1 = (bf16*)d_ws;                       // [MPAD][KPAD]
    bf16* A2 = A1 + (size_t)MPAD * KPAD;          // [MPAD][KPAD]

    build_dct_kernel<<<dim3((MPAD * KPAD + 255) / 256), dim3(256), 0, stream>>>(A1, A2, L);

    const int Mtiles   = (L + 127) / 128;
    const int K2chunks = (L + 31) / 32;
    float* xdct = out + (size_t)BATCH * (size_t)L * D1024;

    // GEMM1: x_dct (fp32, truncated to L rows) from f32 x
    dct_gemm<false><<<dim3(8, Mtiles, BATCH), dim3(256), 0, stream>>>(A1, x,    xdct, L, KPAD / 32, S576);
    // GEMM2: recon (fp32) from fp32 x_dct (reads d_out region GEMM1 just wrote)
    dct_gemm<true ><<<dim3(8, Mtiles, BATCH), dim3(256), 0, stream>>>(A2, xdct, out,  L, K2chunks, L);
}

// Round 4
// 555.997 us; speedup vs baseline: 1.3630x; 1.3630x over previous
//
#include <hip/hip_runtime.h>
#include <hip/hip_bf16.h>
#include <math.h>

typedef __bf16 bf16;
typedef __bf16 bf16x4 __attribute__((ext_vector_type(4)));
typedef __bf16 bf16x8 __attribute__((ext_vector_type(8)));
typedef float floatx4 __attribute__((ext_vector_type(4)));

#define BATCH  64
#define S576   576
#define D1024  1024
#define MPAD   640    // 5 * 128
#define KPAD   576    // 18 * 32 = 9 * 64
#define MSTACK 1280   // stacked A rows: [0,640) = M (recon), [640,1280) = C1 (xdct)

// ============================ fused path =============================

// Fill fp32 tables + bf16 C1 into A_stack rows [640,1280):
//  Cl_f32 [576][640]: Cl[k][l] = cos(pi/L*(l+.5)*k)*scL(k), k<L && l<L else 0
//  C1_f32 [576][576]: C1[k][s] = cos(pi/576*(s+.5)*k)*sc576(k)   (unguarded; Cl guards M sum)
//  A_stack[640+r][c] = (r<L) ? C1[r][c] : 0   (bf16)
__global__ void build_consts_kernel(float* __restrict__ Cl_f32, float* __restrict__ C1_f32,
                                    bf16* __restrict__ A_stack, int L) {
    int idx = blockIdx.x * blockDim.x + threadIdx.x;
    if (idx >= MPAD * MPAD) return;
    int r = idx / MPAD;   // k
    int c = idx % MPAD;   // l or s
    const double PI = 3.14159265358979323846;
    const double dL = (double)L;

    if (r < S576) {
        float v = 0.0f;
        if (r < L && c < L) {
            double sc = (r == 0) ? sqrt(1.0 / dL) : sqrt(2.0 / dL);
            v = (float)(cos(PI / dL * ((double)c + 0.5) * (double)r) * sc);
        }
        Cl_f32[(size_t)r * MPAD + c] = v;
    }
    if (c < S576) {
        double sc = (r == 0) ? sqrt(1.0 / 576.0) : sqrt(2.0 / 576.0);
        float c1 = (float)(cos(PI / 576.0 * ((double)c + 0.5) * (double)r) * sc);
        if (r < S576)
            C1_f32[(size_t)r * S576 + c] = c1;
        // A_stack xdct rows (r = k index in [0,640))
        A_stack[(size_t)(MPAD + r) * KPAD + c] = (r < L) ? (bf16)c1 : (bf16)0.0f;
    }
}

// M[l][s] = sum_{k<L} Cl[k][l] * C1[k][s], fp32 accumulate, bf16 result into
// A_stack rows [0,640). Tile 32x32, block 256, k-chunks of 32.
__global__ __launch_bounds__(256)
void mbuild_f32(const float* __restrict__ Cl, const float* __restrict__ C1,
                bf16* __restrict__ A_stack, int L) {
    __shared__ float ClT[32][33];  // [k][l]
    __shared__ float C1s[32][33];  // [k][s]
    const int t  = threadIdx.x;
    const int l0 = blockIdx.x * 32;   // 20 tiles
    const int s0 = blockIdx.y * 32;   // 18 tiles

    float acc[4] = {0.f, 0.f, 0.f, 0.f};
    const int kch = (L + 31) / 32;    // <= 18, so k <= 575 always in-bounds

    for (int kc = 0; kc < kch; ++kc) {
        const int k0 = kc * 32;
        #pragma unroll
        for (int i = 0; i < 4; ++i) {
            int e = i * 256 + t;
            int kk = e >> 5, cc = e & 31;
            ClT[kk][cc] = Cl[(size_t)(k0 + kk) * MPAD + (l0 + cc)];
            C1s[kk][cc] = C1[(size_t)(k0 + kk) * S576 + (s0 + cc)];
        }
        __syncthreads();
        const int s = t & 31, lb = (t >> 5) * 4;
        #pragma unroll 8
        for (int k = 0; k < 32; ++k) {
            float c1v = C1s[k][s];
            #pragma unroll
            for (int j = 0; j < 4; ++j)
                acc[j] += ClT[k][lb + j] * c1v;
        }
        __syncthreads();
    }
    const int s = t & 31, lb = (t >> 5) * 4;
    #pragma unroll
    for (int j = 0; j < 4; ++j)
        A_stack[(size_t)(l0 + lb + j) * KPAD + (s0 + s)] = (bf16)acc[j];
}

// x [64][576][1024] f32 -> xT [64][1024][576] bf16. 64x64 tiles via LDS.
// T stride 80 elems (160 B): all bf16x8 reads 16B-aligned.
__global__ __launch_bounds__(256)
void transpose_cast_kernel(const float* __restrict__ x, bf16* __restrict__ xT) {
    __shared__ __align__(16) bf16 T[64][80];
    const int t  = threadIdx.x;
    const int d0 = blockIdx.x * 64;
    const int s0 = blockIdx.y * 64;
    const int b  = blockIdx.z;

    const float* xb = x + ((size_t)b * S576 + s0) * D1024 + d0;
    const int sb4 = (t >> 4) * 4;      // 4 consecutive s rows
    const int dl  = (t & 15) * 4;      // 4 consecutive d cols

    float4 v[4];
    #pragma unroll
    for (int i = 0; i < 4; ++i)
        v[i] = *(const float4*)(xb + (size_t)(sb4 + i) * D1024 + dl);

    #pragma unroll
    for (int j = 0; j < 4; ++j) {
        bf16x4 w;
        #pragma unroll
        for (int i = 0; i < 4; ++i)
            w[i] = (bf16)(((const float*)&v[i])[j]);
        *(bf16x4*)&T[dl + j][sb4] = w;   // 8B-aligned (sb4 multiple of 4)
    }
    __syncthreads();

    bf16* xTb = xT + ((size_t)b * D1024 + d0) * KPAD + s0;
    #pragma unroll
    for (int it = 0; it < 2; ++it) {
        int c = it * 256 + t;
        int d = c >> 3, q = c & 7;
        bf16x8 rv = *(const bf16x8*)&T[d][q * 8];   // 16B-aligned: d*160 + q*16
        *(bf16x8*)(xTb + (size_t)d * KPAD + q * 8) = rv;
    }
}

// Fused GEMM: Out_stack[m][n] = sum_k A_stack[m][k] * xT[b][n][k].
// Stack rows [0,640) -> recon, [640,1280) -> xdct. Tile 128x128, BK=64.
// LDS stride 80 elems (160 B): every b128 access 16B-aligned.
__global__ __launch_bounds__(256)
void fused_gemm(const bf16* __restrict__ A_stack, const bf16* __restrict__ xT,
                float* __restrict__ out, int L) {
    __shared__ __align__(16) bf16 Asm[128][80], Bsm[128][80];

    const int t = threadIdx.x;
    const int lane = t & 63, wave = t >> 6;
    const int wm = (wave >> 1) * 64, wn = (wave & 1) * 64;
    const int quad = lane >> 4, l16 = lane & 15;
    const int n0 = blockIdx.x * 128;
    const int m0 = blockIdx.y * 128;
    const int b  = blockIdx.z;

    const bf16* Abase = A_stack + (size_t)m0 * KPAD;
    const bf16* Bbase = xT + ((size_t)b * D1024 + n0) * KPAD;

    floatx4 acc[4][4];
    #pragma unroll
    for (int i = 0; i < 4; ++i)
        #pragma unroll
        for (int j = 0; j < 4; ++j)
            #pragma unroll
            for (int r = 0; r < 4; ++r)
                acc[i][j][r] = 0.0f;

    for (int kc = 0; kc < KPAD / 64; ++kc) {
        const int k0 = kc * 64;
        #pragma unroll
        for (int it = 0; it < 4; ++it) {
            int c = it * 256 + t;
            int row = c >> 3, q = c & 7;
            bf16x8 av = *(const bf16x8*)(Abase + (size_t)row * KPAD + k0 + q * 8);
            *(bf16x8*)&Asm[row][q * 8] = av;    // row*160 + q*16: aligned
        }
        #pragma unroll
        for (int it = 0; it < 4; ++it) {
            int c = it * 256 + t;
            int row = c >> 3, q = c & 7;
            bf16x8 bv = *(const bf16x8*)(Bbase + (size_t)row * KPAD + k0 + q * 8);
            *(bf16x8*)&Bsm[row][q * 8] = bv;
        }
        __syncthreads();

        #pragma unroll
        for (int ks = 0; ks < 2; ++ks) {
            bf16x8 af[4], bfr[4];
            #pragma unroll
            for (int mt = 0; mt < 4; ++mt)
                af[mt] = *(const bf16x8*)&Asm[wm + mt * 16 + l16][ks * 32 + quad * 8];
            #pragma unroll
            for (int nt = 0; nt < 4; ++nt)
                bfr[nt] = *(const bf16x8*)&Bsm[wn + nt * 16 + l16][ks * 32 + quad * 8];
            #pragma unroll
            for (int mt = 0; mt < 4; ++mt)
                #pragma unroll
                for (int nt = 0; nt < 4; ++nt)
                    acc[mt][nt] = __builtin_amdgcn_mfma_f32_16x16x32_bf16(
                                      af[mt], bfr[nt], acc[mt][nt], 0, 0, 0);
        }
        __syncthreads();
    }

    const size_t halfout = (size_t)BATCH * (size_t)L * D1024;
    #pragma unroll
    for (int mt = 0; mt < 4; ++mt)
        #pragma unroll
        for (int r = 0; r < 4; ++r) {
            int sr = m0 + wm + mt * 16 + quad * 4 + r;  // 16-row groups never straddle 640
            int m = sr;
            float* dst = out;
            if (sr >= MPAD) { m = sr - MPAD; dst = out + halfout; }
            if (m < L) {
                size_t ro = ((size_t)b * (size_t)L + m) * D1024 + n0 + wn;
                #pragma unroll
                for (int nt = 0; nt < 4; ++nt)
                    dst[ro + nt * 16 + l16] = acc[mt][nt][r];
            }
        }
}

// ====================== fallback path (round-2, proven end-to-end) ======================

__global__ void build_dct_kernel(bf16* __restrict__ A1, bf16* __restrict__ A2, int L) {
    int idx = blockIdx.x * blockDim.x + threadIdx.x;
    if (idx >= MPAD * KPAD) return;
    int m = idx / KPAD;
    int s = idx % KPAD;
    const double PI = 3.14159265358979323846;
    float v1 = 0.0f;
    if (m < L) {
        double scale = (m == 0) ? sqrt(1.0 / 576.0) : sqrt(2.0 / 576.0);
        v1 = (float)(cos(PI / 576.0 * ((double)s + 0.5) * (double)m) * scale);
    }
    A1[idx] = (bf16)v1;
    float v2 = 0.0f;
    if (m < L && s < L) {
        double dL = (double)L;
        double scale = (s == 0) ? sqrt(1.0 / dL) : sqrt(2.0 / dL);
        v2 = (float)(cos(PI / dL * ((double)m + 0.5) * (double)s) * scale);
    }
    A2[idx] = (bf16)v2;
}

template<bool GUARD_K>
__global__ __launch_bounds__(256)
void dct_gemm(const bf16* __restrict__ A, const float* __restrict__ B,
              float* __restrict__ Out, int L, int Kchunks, int bRows)
{
    __shared__ __align__(16) bf16 Asm[128][40];
    __shared__ __align__(16) bf16 Bsm[128][40];

    const int tid  = threadIdx.x;
    const int lane = tid & 63;
    const int wave = tid >> 6;
    const int wm   = (wave >> 1) * 64;
    const int wn   = (wave & 1) * 64;
    const int quad = lane >> 4;
    const int l16  = lane & 15;

    const int n0 = blockIdx.x * 128;
    const int m0 = blockIdx.y * 128;
    const int batch = blockIdx.z;

    const float* __restrict__ Bf = B + (size_t)batch * (size_t)bRows * D1024;

    floatx4 acc[4][4];
    #pragma unroll
    for (int i = 0; i < 4; ++i)
        #pragma unroll
        for (int j = 0; j < 4; ++j)
            #pragma unroll
            for (int r = 0; r < 4; ++r)
                acc[i][j][r] = 0.0f;

    for (int kc = 0; kc < Kchunks; ++kc) {
        const int k0 = kc * 32;
        #pragma unroll
        for (int it = 0; it < 2; ++it) {
            int c = it * 256 + tid;
            int m = c >> 2;
            int q = c & 3;
            bf16x8 av = *(const bf16x8*)(A + (size_t)(m0 + m) * KPAD + (k0 + q * 8));
            *(bf16x8*)&Asm[m][q * 8] = av;
        }
        #pragma unroll
        for (int it = 0; it < 2; ++it) {
            int g  = it * 256 + tid;
            int d  = g & 127;
            int s0 = (g >> 7) * 8;
            bf16x8 pk;
            #pragma unroll
            for (int j = 0; j < 8; ++j) {
                int k = k0 + s0 + j;
                float v = (!GUARD_K || k < bRows) ? Bf[(size_t)k * D1024 + (n0 + d)] : 0.0f;
                pk[j] = (bf16)v;
            }
            *(bf16x8*)&Bsm[d][s0] = pk;
        }
        __syncthreads();

        bf16x8 af[4], bfr[4];
        #pragma unroll
        for (int mt = 0; mt < 4; ++mt)
            af[mt] = *(const bf16x8*)&Asm[wm + mt * 16 + l16][quad * 8];
        #pragma unroll
        for (int nt = 0; nt < 4; ++nt)
            bfr[nt] = *(const bf16x8*)&Bsm[wn + nt * 16 + l16][quad * 8];

        #pragma unroll
        for (int mt = 0; mt < 4; ++mt)
            #pragma unroll
            for (int nt = 0; nt < 4; ++nt)
                acc[mt][nt] = __builtin_amdgcn_mfma_f32_16x16x32_bf16(
                                  af[mt], bfr[nt], acc[mt][nt], 0, 0, 0);
        __syncthreads();
    }

    const size_t obase = (size_t)batch * (size_t)L * D1024;
    #pragma unroll
    for (int mt = 0; mt < 4; ++mt) {
        #pragma unroll
        for (int r = 0; r < 4; ++r) {
            int m = m0 + wm + mt * 16 + quad * 4 + r;
            if (m < L) {
                size_t rowoff = obase + (size_t)m * D1024;
                #pragma unroll
                for (int nt = 0; nt < 4; ++nt) {
                    int n = n0 + wn + nt * 16 + l16;
                    Out[rowoff + n] = acc[mt][nt][r];
                }
            }
        }
    }
}

// ================================ launch ================================

extern "C" void kernel_launch(void* const* d_in, const int* in_sizes, int n_in,
                              void* d_out, int out_size, void* d_ws, size_t ws_size,
                              hipStream_t stream)
{
    const float* x = (const float*)d_in[0];
    float* out = (float*)d_out;

    const int L = out_size / (2 * BATCH * D1024);
    if (L <= 0) return;

    // ws layout (all 16B-aligned offsets):
    //  Cl_f32  [576][640] f32   1,474,560 B
    //  C1_f32  [576][576] f32   1,327,104 B
    //  A_stack [1280][576] bf16 1,474,560 B
    //  xT      [64][1024][576] bf16  75,497,472 B
    const size_t CL_B  = (size_t)S576 * MPAD * sizeof(float);
    const size_t C1_B  = (size_t)S576 * S576 * sizeof(float);
    const size_t AS_B  = (size_t)MSTACK * KPAD * sizeof(bf16);
    const size_t XT_B  = (size_t)BATCH * D1024 * KPAD * sizeof(bf16);
    const size_t need  = CL_B + C1_B + AS_B + XT_B;   // ~79.8 MB

    if (ws_size >= need) {
        float* Cl_f32  = (float*)d_ws;
        float* C1_f32  = (float*)((char*)d_ws + CL_B);
        bf16*  A_stack = (bf16*)((char*)d_ws + CL_B + C1_B);
        bf16*  xT      = (bf16*)((char*)d_ws + CL_B + C1_B + AS_B);

        build_consts_kernel<<<dim3((MPAD * MPAD + 255) / 256), dim3(256), 0, stream>>>(
            Cl_f32, C1_f32, A_stack, L);
        transpose_cast_kernel<<<dim3(D1024 / 64, S576 / 64, BATCH), dim3(256), 0, stream>>>(x, xT);
        mbuild_f32<<<dim3(MPAD / 32, S576 / 32), dim3(256), 0, stream>>>(Cl_f32, C1_f32, A_stack, L);
        fused_gemm<<<dim3(D1024 / 128, MSTACK / 128, BATCH), dim3(256), 0, stream>>>(
            A_stack, xT, out, L);
    } else {
        // fallback: round-2 two-GEMM path (needs ~1.5 MB ws), proven end-to-end
        bf16* A1 = (bf16*)d_ws;
        bf16* A2 = A1 + (size_t)MPAD * KPAD;

        build_dct_kernel<<<dim3((MPAD * KPAD + 255) / 256), dim3(256), 0, stream>>>(A1, A2, L);

        const int Mtiles   = (L + 127) / 128;
        const int K2chunks = (L + 31) / 32;
        float* xdct = out + (size_t)BATCH * (size_t)L * D1024;

        dct_gemm<false><<<dim3(8, Mtiles, BATCH), dim3(256), 0, stream>>>(A1, x,    xdct, L, KPAD / 32, S576);
        dct_gemm<true ><<<dim3(8, Mtiles, BATCH), dim3(256), 0, stream>>>(A2, xdct, out,  L, K2chunks, L);
    }
}